// Round 1
// baseline (231.936 us; speedup 1.0000x reference)
//
#include <hip/hip_runtime.h>

#define LQN 21760
#define LVN 21760
#define BATCH 2
#define CDIM 256
#define HDN 8
#define DDIM 32

typedef __attribute__((ext_vector_type(8))) short short8;
typedef __attribute__((ext_vector_type(4))) float f32x4;

__device__ __forceinline__ unsigned short f2bf(float f) {
  union { float f; unsigned int u; } v; v.f = f;
  unsigned int r = v.u + 0x7fffu + ((v.u >> 16) & 1u);
  return (unsigned short)(r >> 16);
}
__device__ __forceinline__ float bf2f(unsigned short h) {
  union { unsigned int u; float f; } v; v.u = ((unsigned int)h) << 16; return v.f;
}

// ---------------- prep: transpose weights to bf16 W^T[n][k] ----------------
__global__ __launch_bounds__(256) void prep_kernel(
    const float* __restrict__ Wval, const float* __restrict__ Woff,
    const float* __restrict__ Wattn, const float* __restrict__ Wout,
    unsigned short* __restrict__ wtval, unsigned short* __restrict__ wtoa,
    unsigned short* __restrict__ wtout) {
  int idx = blockIdx.x * 256 + threadIdx.x;  // 0 .. 98303
  int n = idx >> 8, k = idx & 255;
  if (idx < 65536) {
    wtval[idx] = f2bf(Wval[k * 256 + n]);
    wtout[idx] = f2bf(Wout[k * 256 + n]);
  }
  if (idx < 98304) {
    float v = (n < 256) ? Woff[k * 256 + n] : Wattn[k * 128 + (n - 256)];
    wtoa[idx] = f2bf(v);
  }
}

// ---------------- GEMM: C[M,N] = A[M,256] @ W[256,N] (+epilogue) ------------
// MODE 0: A=value(f32) -> v_bf16[B,HD,LV,D] scatter (+b_val)
// MODE 1: A=query(f32) -> offattn bf16 [M,384] (+b_off/b_attn)
// MODE 2: A=msout(bf16) -> d_out f32 [M,256] (+b_out +query residual)
template <int MODE>
__global__ __launch_bounds__(256) void gemm_kernel(
    const float* __restrict__ Af32, const unsigned short* __restrict__ Abf,
    const unsigned short* __restrict__ Wt, const float* __restrict__ bias0,
    const float* __restrict__ bias1, const float* __restrict__ resid,
    unsigned short* __restrict__ out_bf, float* __restrict__ out_f32) {
  constexpr int K = 256;
  constexpr int LDSS = 56;  // padded row stride (shorts): 112B, 16B aligned
  __shared__ unsigned short lsA[64 * LDSS];
  __shared__ unsigned short lsB[64 * LDSS];
  const int m0 = blockIdx.x * 64;
  const int n0 = blockIdx.y * 64;
  const int t = threadIdx.x;
  const int w = t >> 6;
  const int l = t & 63;
  const int fr = l & 15;
  const int kk = (l >> 4) * 8;

  f32x4 acc[4];
#pragma unroll
  for (int c = 0; c < 4; ++c) acc[c] = (f32x4){0.f, 0.f, 0.f, 0.f};

  const int srow = t >> 2;
  const int sk = (t & 3) * 8;

  for (int kt = 0; kt < K / 32; ++kt) {
    const int k0 = kt * 32;
    // ---- stage A (64x32) ----
    if (MODE == 2) {
      *(uint4*)(lsA + srow * LDSS + sk) =
          *(const uint4*)(Abf + (size_t)(m0 + srow) * K + k0 + sk);
    } else {
      const float* ap = Af32 + (size_t)(m0 + srow) * K + k0 + sk;
      float4 f0 = *(const float4*)(ap);
      float4 f1 = *(const float4*)(ap + 4);
      uint4 pk;
      pk.x = (unsigned)f2bf(f0.x) | ((unsigned)f2bf(f0.y) << 16);
      pk.y = (unsigned)f2bf(f0.z) | ((unsigned)f2bf(f0.w) << 16);
      pk.z = (unsigned)f2bf(f1.x) | ((unsigned)f2bf(f1.y) << 16);
      pk.w = (unsigned)f2bf(f1.z) | ((unsigned)f2bf(f1.w) << 16);
      *(uint4*)(lsA + srow * LDSS + sk) = pk;
    }
    // ---- stage B (rows = output cols n, 64x32) from W^T[n][k] ----
    *(uint4*)(lsB + srow * LDSS + sk) =
        *(const uint4*)(Wt + (size_t)(n0 + srow) * K + k0 + sk);
    __syncthreads();
    const short8 a = *(const short8*)(lsA + (w * 16 + fr) * LDSS + kk);
#pragma unroll
    for (int c = 0; c < 4; ++c) {
      const short8 b = *(const short8*)(lsB + (c * 16 + fr) * LDSS + kk);
      acc[c] = __builtin_amdgcn_mfma_f32_16x16x32_bf16(a, b, acc[c], 0, 0, 0);
    }
    __syncthreads();
  }

  const int fq = l >> 4;
#pragma unroll
  for (int c = 0; c < 4; ++c) {
#pragma unroll
    for (int r = 0; r < 4; ++r) {
      const int row = m0 + w * 16 + fq * 4 + r;
      const int col = n0 + c * 16 + fr;
      float v = acc[c][r];
      if (MODE == 0) {
        v += bias0[col];
        const int bb = (row >= LVN) ? 1 : 0;
        const int i = row - bb * LVN;
        const int h = col >> 5, d = col & 31;
        out_bf[(((size_t)(bb * HDN + h) * LVN + i) << 5) + d] = f2bf(v);
      } else if (MODE == 1) {
        const float bias = (col < 256) ? bias0[col] : bias1[col - 256];
        out_bf[(size_t)row * 384 + col] = f2bf(v + bias);
      } else {
        const size_t o = (size_t)row * 256 + col;
        out_f32[o] = v + bias0[col] + resid[o];
      }
    }
  }
}

// ---------------- sampler: one wave per query; 8 lanes/head, 4 dims/lane ----
__global__ __launch_bounds__(256) void sampler_kernel(
    const unsigned short* __restrict__ vbf,      // [B,HD,LV,32] bf16
    const unsigned short* __restrict__ offattn,  // [B*LQ,384] bf16
    const float* __restrict__ refpts,            // [B,LQ,4,2] f32
    unsigned short* __restrict__ msout) {        // [B*LQ,256] bf16
  const int t = threadIdx.x;
  const int qi = blockIdx.x * 4 + (t >> 6);
  const int lane = t & 63;
  const int h = lane >> 3;
  const int d0 = (lane & 7) * 4;
  const int bb = (qi >= LQN) ? 1 : 0;

  const unsigned short* oa = offattn + (size_t)qi * 384;

  // logits: 16 bf16 at col 256 + h*16 (same addr across the 8 lanes -> bcast)
  float lg[16];
  {
    const uint4 r0 = *(const uint4*)(oa + 256 + h * 16);
    const uint4 r1 = *(const uint4*)(oa + 256 + h * 16 + 8);
    const unsigned int ww[8] = {r0.x, r0.y, r0.z, r0.w, r1.x, r1.y, r1.z, r1.w};
#pragma unroll
    for (int j = 0; j < 8; ++j) {
      lg[2 * j] = bf2f((unsigned short)(ww[j] & 0xffffu));
      lg[2 * j + 1] = bf2f((unsigned short)(ww[j] >> 16));
    }
  }
  float mx = lg[0];
#pragma unroll
  for (int j = 1; j < 16; ++j) mx = fmaxf(mx, lg[j]);
  float ssum = 0.f;
#pragma unroll
  for (int j = 0; j < 16; ++j) {
    lg[j] = __expf(lg[j] - mx);
    ssum += lg[j];
  }
  const float inv = 1.f / ssum;

  float a0 = 0.f, a1 = 0.f, a2 = 0.f, a3 = 0.f;
  const float* ref = refpts + (size_t)qi * 8;
  const unsigned short* vhead = vbf + (size_t)(bb * HDN + h) * LVN * DDIM + d0;

  const int WLs[4] = {128, 64, 32, 16};
  const int HLs[4] = {128, 64, 32, 16};
  const int STs[4] = {0, 16384, 20480, 21504};

#pragma unroll
  for (int lvl = 0; lvl < 4; ++lvl) {
    const int Wl = WLs[lvl], Hl = HLs[lvl], st = STs[lvl];
    const float rx = ref[lvl * 2 + 0];
    const float ry = ref[lvl * 2 + 1];
    const uint4 ov = *(const uint4*)(oa + h * 32 + lvl * 8);  // 4 (x,y) pairs
    const unsigned int op[4] = {ov.x, ov.y, ov.z, ov.w};
#pragma unroll
    for (int p = 0; p < 4; ++p) {
      const float ox = bf2f((unsigned short)(op[p] & 0xffffu));
      const float oy = bf2f((unsigned short)(op[p] >> 16));
      // loc*W - 0.5 == ref*W + off - 0.5 (norm folds out)
      const float xs = fmaf(rx, (float)Wl, ox) - 0.5f;
      const float ys = fmaf(ry, (float)Hl, oy) - 0.5f;
      const float x0f = floorf(xs), y0f = floorf(ys);
      const float lx = xs - x0f, ly = ys - y0f;
      const int x0 = (int)x0f, y0 = (int)y0f;
      const float aw = lg[lvl * 4 + p] * inv;
      const float w00 = aw * (1.f - lx) * (1.f - ly);
      const float w01 = aw * lx * (1.f - ly);
      const float w10 = aw * (1.f - lx) * ly;
      const float w11 = aw * lx * ly;
      const bool vx0 = (x0 >= 0) && (x0 < Wl);
      const bool vx1 = (x0 + 1 >= 0) && (x0 + 1 < Wl);
      const bool vy0 = (y0 >= 0) && (y0 < Hl);
      const bool vy1 = (y0 + 1 >= 0) && (y0 + 1 < Hl);

#define FETCH_CORNER(cond, wgt, iy, ix)                                     \
  if (cond) {                                                               \
    const unsigned short* pv =                                              \
        vhead + (size_t)(st + (iy) * Wl + (ix)) * DDIM;                     \
    const uint2 rv = *(const uint2*)(pv);                                   \
    a0 += (wgt) * bf2f((unsigned short)(rv.x & 0xffffu));                   \
    a1 += (wgt) * bf2f((unsigned short)(rv.x >> 16));                       \
    a2 += (wgt) * bf2f((unsigned short)(rv.y & 0xffffu));                   \
    a3 += (wgt) * bf2f((unsigned short)(rv.y >> 16));                       \
  }

      FETCH_CORNER(vy0 && vx0, w00, y0, x0)
      FETCH_CORNER(vy0 && vx1, w01, y0, x0 + 1)
      FETCH_CORNER(vy1 && vx0, w10, y0 + 1, x0)
      FETCH_CORNER(vy1 && vx1, w11, y0 + 1, x0 + 1)
#undef FETCH_CORNER
    }
  }

  uint2 outv;
  outv.x = (unsigned)f2bf(a0) | ((unsigned)f2bf(a1) << 16);
  outv.y = (unsigned)f2bf(a2) | ((unsigned)f2bf(a3) << 16);
  *(uint2*)(msout + (size_t)qi * 256 + h * 32 + d0) = outv;
}

// ---------------- launch ----------------------------------------------------
extern "C" void kernel_launch(void* const* d_in, const int* in_sizes, int n_in,
                              void* d_out, int out_size, void* d_ws,
                              size_t ws_size, hipStream_t stream) {
  const float* query = (const float*)d_in[0];
  const float* refpts = (const float*)d_in[1];
  const float* value = (const float*)d_in[2];
  const float* W_off = (const float*)d_in[5];
  const float* b_off = (const float*)d_in[6];
  const float* W_attn = (const float*)d_in[7];
  const float* b_attn = (const float*)d_in[8];
  const float* W_val = (const float*)d_in[9];
  const float* b_val = (const float*)d_in[10];
  const float* W_out = (const float*)d_in[11];
  const float* b_out = (const float*)d_in[12];
  float* out = (float*)d_out;

  char* ws = (char*)d_ws;
  unsigned short* wtval = (unsigned short*)(ws);                    // 256x256 bf16
  unsigned short* wtoa = (unsigned short*)(ws + 131072);            // 384x256 bf16
  unsigned short* wtout = (unsigned short*)(ws + 327680);           // 256x256 bf16
  unsigned short* vbf = (unsigned short*)(ws + 458752);             // 22282240 B
  unsigned short* offattn = (unsigned short*)(ws + 22740992);       // 33423360 B
  unsigned short* msout = (unsigned short*)(ws + 56164352);         // 22282240 B

  prep_kernel<<<384, 256, 0, stream>>>(W_val, W_off, W_attn, W_out, wtval, wtoa,
                                       wtout);
  gemm_kernel<0><<<dim3(680, 4), 256, 0, stream>>>(
      value, nullptr, wtval, b_val, nullptr, nullptr, vbf, nullptr);
  gemm_kernel<1><<<dim3(680, 6), 256, 0, stream>>>(
      query, nullptr, wtoa, b_off, b_attn, nullptr, offattn, nullptr);
  sampler_kernel<<<10880, 256, 0, stream>>>(vbf, offattn, refpts, msout);
  gemm_kernel<2><<<dim3(680, 4), 256, 0, stream>>>(
      nullptr, msout, wtout, b_out, nullptr, query, nullptr, out);
}

// Round 2
// 196.600 us; speedup vs baseline: 1.1797x; 1.1797x over previous
//
#include <hip/hip_runtime.h>

#define LQN 21760
#define LVN 21760
#define BATCH 2
#define CDIM 256
#define HDN 8
#define DDIM 32

typedef __attribute__((ext_vector_type(8))) short short8;
typedef __attribute__((ext_vector_type(4))) float f32x4;

__device__ __forceinline__ unsigned short f2bf(float f) {
  union { float f; unsigned int u; } v; v.f = f;
  unsigned int r = v.u + 0x7fffu + ((v.u >> 16) & 1u);
  return (unsigned short)(r >> 16);
}
__device__ __forceinline__ float bf2f(unsigned short h) {
  union { unsigned int u; float f; } v; v.u = ((unsigned int)h) << 16; return v.f;
}
__device__ __forceinline__ float bflo(unsigned int u) {
  union { unsigned int u; float f; } v; v.u = u << 16; return v.f;
}
__device__ __forceinline__ float bfhi(unsigned int u) {
  union { unsigned int u; float f; } v; v.u = u & 0xffff0000u; return v.f;
}

// ---------------- prep: transpose weights to bf16 W^T[n][k] ----------------
__global__ __launch_bounds__(256) void prep_kernel(
    const float* __restrict__ Wval, const float* __restrict__ Woff,
    const float* __restrict__ Wattn, const float* __restrict__ Wout,
    unsigned short* __restrict__ wtval, unsigned short* __restrict__ wtoa,
    unsigned short* __restrict__ wtout) {
  int idx = blockIdx.x * 256 + threadIdx.x;  // 0 .. 98303
  int n = idx >> 8, k = idx & 255;
  if (idx < 65536) {
    wtval[idx] = f2bf(Wval[k * 256 + n]);
    wtout[idx] = f2bf(Wout[k * 256 + n]);
  }
  if (idx < 98304) {
    float v = (n < 256) ? Woff[k * 256 + n] : Wattn[k * 128 + (n - 256)];
    wtoa[idx] = f2bf(v);
  }
}

// ---------------- GEMM: C[M,N] = A[M,256] @ W[256,N] (+epilogue) ------------
template <int MODE>
__global__ __launch_bounds__(256) void gemm_kernel(
    const float* __restrict__ Af32, const unsigned short* __restrict__ Abf,
    const unsigned short* __restrict__ Wt, const float* __restrict__ bias0,
    const float* __restrict__ bias1, const float* __restrict__ resid,
    unsigned short* __restrict__ out_bf, float* __restrict__ out_f32) {
  constexpr int K = 256;
  constexpr int LDSS = 56;  // padded row stride (shorts): 112B, 16B aligned
  __shared__ unsigned short lsA[64 * LDSS];
  __shared__ unsigned short lsB[64 * LDSS];
  const int m0 = blockIdx.x * 64;
  const int n0 = blockIdx.y * 64;
  const int t = threadIdx.x;
  const int w = t >> 6;
  const int l = t & 63;
  const int fr = l & 15;
  const int kk = (l >> 4) * 8;

  f32x4 acc[4];
#pragma unroll
  for (int c = 0; c < 4; ++c) acc[c] = (f32x4){0.f, 0.f, 0.f, 0.f};

  const int srow = t >> 2;
  const int sk = (t & 3) * 8;

  for (int kt = 0; kt < K / 32; ++kt) {
    const int k0 = kt * 32;
    if (MODE == 2) {
      *(uint4*)(lsA + srow * LDSS + sk) =
          *(const uint4*)(Abf + (size_t)(m0 + srow) * K + k0 + sk);
    } else {
      const float* ap = Af32 + (size_t)(m0 + srow) * K + k0 + sk;
      float4 f0 = *(const float4*)(ap);
      float4 f1 = *(const float4*)(ap + 4);
      uint4 pk;
      pk.x = (unsigned)f2bf(f0.x) | ((unsigned)f2bf(f0.y) << 16);
      pk.y = (unsigned)f2bf(f0.z) | ((unsigned)f2bf(f0.w) << 16);
      pk.z = (unsigned)f2bf(f1.x) | ((unsigned)f2bf(f1.y) << 16);
      pk.w = (unsigned)f2bf(f1.z) | ((unsigned)f2bf(f1.w) << 16);
      *(uint4*)(lsA + srow * LDSS + sk) = pk;
    }
    *(uint4*)(lsB + srow * LDSS + sk) =
        *(const uint4*)(Wt + (size_t)(n0 + srow) * K + k0 + sk);
    __syncthreads();
    const short8 a = *(const short8*)(lsA + (w * 16 + fr) * LDSS + kk);
#pragma unroll
    for (int c = 0; c < 4; ++c) {
      const short8 b = *(const short8*)(lsB + (c * 16 + fr) * LDSS + kk);
      acc[c] = __builtin_amdgcn_mfma_f32_16x16x32_bf16(a, b, acc[c], 0, 0, 0);
    }
    __syncthreads();
  }

  const int fq = l >> 4;
#pragma unroll
  for (int c = 0; c < 4; ++c) {
#pragma unroll
    for (int r = 0; r < 4; ++r) {
      const int row = m0 + w * 16 + fq * 4 + r;
      const int col = n0 + c * 16 + fr;
      float v = acc[c][r];
      if (MODE == 0) {
        v += bias0[col];
        const int bb = (row >= LVN) ? 1 : 0;
        const int i = row - bb * LVN;
        const int h = col >> 5, d = col & 31;
        out_bf[(((size_t)(bb * HDN + h) * LVN + i) << 5) + d] = f2bf(v);
      } else if (MODE == 1) {
        const float bias = (col < 256) ? bias0[col] : bias1[col - 256];
        out_bf[(size_t)row * 384 + col] = f2bf(v + bias);
      } else {
        const size_t o = (size_t)row * 256 + col;
        out_f32[o] = v + bias0[col] + resid[o];
      }
    }
  }
}

// ---------------- sampler: 2 queries/wave; 4 lanes/head, 8 dims/lane -------
__global__ __launch_bounds__(256) void sampler_kernel(
    const unsigned short* __restrict__ vbf,      // [B,HD,LV,32] bf16
    const unsigned short* __restrict__ offattn,  // [B*LQ,384] bf16
    const float* __restrict__ refpts,            // [B,LQ,4,2] f32
    unsigned short* __restrict__ msout) {        // [B*LQ,256] bf16
  const int t = threadIdx.x;
  const int lane = t & 63;
  const int qi = blockIdx.x * 8 + (t >> 6) * 2 + (lane >> 5);
  const int l5 = lane & 31;
  const int h = l5 >> 2;
  const int d0 = (l5 & 3) * 8;
  const int bb = (qi >= LQN) ? 1 : 0;

  const unsigned short* oa = offattn + (size_t)qi * 384;

  // ---- softmax over 16 logits for this (q,h); fold 1/sum in ----
  float lg[16];
  {
    const uint4 r0 = *(const uint4*)(oa + 256 + h * 16);
    const uint4 r1 = *(const uint4*)(oa + 256 + h * 16 + 8);
    const unsigned int ww[8] = {r0.x, r0.y, r0.z, r0.w, r1.x, r1.y, r1.z, r1.w};
#pragma unroll
    for (int j = 0; j < 8; ++j) {
      lg[2 * j] = bflo(ww[j]);
      lg[2 * j + 1] = bfhi(ww[j]);
    }
  }
  float mx = lg[0];
#pragma unroll
  for (int j = 1; j < 16; ++j) mx = fmaxf(mx, lg[j]);
  float ssum = 0.f;
#pragma unroll
  for (int j = 0; j < 16; ++j) {
    lg[j] = __expf(lg[j] - mx);
    ssum += lg[j];
  }
  const float inv = 1.f / ssum;
#pragma unroll
  for (int j = 0; j < 16; ++j) lg[j] *= inv;

  // lane-constant 32-bit element offset into vbf
  const unsigned int headbase =
      (unsigned int)(bb * HDN + h) * (LVN * DDIM) + (unsigned int)d0;

  float acc[8];
#pragma unroll
  for (int j = 0; j < 8; ++j) acc[j] = 0.f;

  const float4 refA = *(const float4*)(refpts + (size_t)qi * 8);
  const float4 refB = *(const float4*)(refpts + (size_t)qi * 8 + 4);
  const float rxs[4] = {refA.x, refA.z, refB.x, refB.z};
  const float rys[4] = {refA.y, refA.w, refB.y, refB.w};

  const int WLs[4] = {128, 64, 32, 16};
  const int LGW[4] = {7, 6, 5, 4};
  const int STs[4] = {0, 16384, 20480, 21504};

#pragma unroll
  for (int lvl = 0; lvl < 4; ++lvl) {
    const int Wl = WLs[lvl], Hl = WLs[lvl], st = STs[lvl], lw = LGW[lvl];
    const float fw = (float)Wl, fh = (float)Hl;
    const float rx = rxs[lvl], ry = rys[lvl];
    const uint4 ov = *(const uint4*)(oa + h * 32 + lvl * 8);
    const unsigned int op[4] = {ov.x, ov.y, ov.z, ov.w};
#pragma unroll
    for (int p = 0; p < 4; ++p) {
      const float ox = bflo(op[p]);
      const float oy = bfhi(op[p]);
      const float xs = fmaf(rx, fw, ox) - 0.5f;
      const float ys = fmaf(ry, fh, oy) - 0.5f;
      const float x0f = floorf(xs), y0f = floorf(ys);
      const float lx = xs - x0f, ly = ys - y0f;
      const int x0 = (int)x0f, y0 = (int)y0f;
      const float aw = lg[lvl * 4 + p];
      const float wy1 = aw * ly, wy0 = aw - wy1;
      float w00 = wy0 - wy0 * lx, w01 = wy0 * lx;
      float w10 = wy1 - wy1 * lx, w11 = wy1 * lx;
      const bool vx0 = (unsigned)x0 < (unsigned)Wl;
      const bool vx1 = (unsigned)(x0 + 1) < (unsigned)Wl;
      const bool vy0 = (unsigned)y0 < (unsigned)Hl;
      const bool vy1 = (unsigned)(y0 + 1) < (unsigned)Hl;
      w00 = (vy0 && vx0) ? w00 : 0.f;
      w01 = (vy0 && vx1) ? w01 : 0.f;
      w10 = (vy1 && vx0) ? w10 : 0.f;
      w11 = (vy1 && vx1) ? w11 : 0.f;
      const int x0c = min(max(x0, 0), Wl - 1);
      const int x1c = min(max(x0 + 1, 0), Wl - 1);
      const int y0c = min(max(y0, 0), Hl - 1);
      const int y1c = min(max(y0 + 1, 0), Hl - 1);
      const unsigned int row0 =
          headbase + (((unsigned)(st + (y0c << lw))) << 5);
      const unsigned int row1 =
          headbase + (((unsigned)(st + (y1c << lw))) << 5);
      const uint4 r00 = *(const uint4*)(vbf + row0 + ((unsigned)x0c << 5));
      const uint4 r01 = *(const uint4*)(vbf + row0 + ((unsigned)x1c << 5));
      const uint4 r10 = *(const uint4*)(vbf + row1 + ((unsigned)x0c << 5));
      const uint4 r11 = *(const uint4*)(vbf + row1 + ((unsigned)x1c << 5));

#define ACCUM(rv, wgt)                          \
  acc[0] += (wgt)*bflo(rv.x);                   \
  acc[1] += (wgt)*bfhi(rv.x);                   \
  acc[2] += (wgt)*bflo(rv.y);                   \
  acc[3] += (wgt)*bfhi(rv.y);                   \
  acc[4] += (wgt)*bflo(rv.z);                   \
  acc[5] += (wgt)*bfhi(rv.z);                   \
  acc[6] += (wgt)*bflo(rv.w);                   \
  acc[7] += (wgt)*bfhi(rv.w);

      ACCUM(r00, w00)
      ACCUM(r01, w01)
      ACCUM(r10, w10)
      ACCUM(r11, w11)
#undef ACCUM
    }
  }

  uint4 outv;
  outv.x = (unsigned)f2bf(acc[0]) | ((unsigned)f2bf(acc[1]) << 16);
  outv.y = (unsigned)f2bf(acc[2]) | ((unsigned)f2bf(acc[3]) << 16);
  outv.z = (unsigned)f2bf(acc[4]) | ((unsigned)f2bf(acc[5]) << 16);
  outv.w = (unsigned)f2bf(acc[6]) | ((unsigned)f2bf(acc[7]) << 16);
  *(uint4*)(msout + (size_t)qi * 256 + h * 32 + d0) = outv;
}

// ---------------- launch ----------------------------------------------------
extern "C" void kernel_launch(void* const* d_in, const int* in_sizes, int n_in,
                              void* d_out, int out_size, void* d_ws,
                              size_t ws_size, hipStream_t stream) {
  const float* query = (const float*)d_in[0];
  const float* refpts = (const float*)d_in[1];
  const float* value = (const float*)d_in[2];
  const float* W_off = (const float*)d_in[5];
  const float* b_off = (const float*)d_in[6];
  const float* W_attn = (const float*)d_in[7];
  const float* b_attn = (const float*)d_in[8];
  const float* W_val = (const float*)d_in[9];
  const float* b_val = (const float*)d_in[10];
  const float* W_out = (const float*)d_in[11];
  const float* b_out = (const float*)d_in[12];
  float* out = (float*)d_out;

  char* ws = (char*)d_ws;
  unsigned short* wtval = (unsigned short*)(ws);                    // 256x256 bf16
  unsigned short* wtoa = (unsigned short*)(ws + 131072);            // 384x256 bf16
  unsigned short* wtout = (unsigned short*)(ws + 327680);           // 256x256 bf16
  unsigned short* vbf = (unsigned short*)(ws + 458752);             // 22282240 B
  unsigned short* offattn = (unsigned short*)(ws + 22740992);       // 33423360 B
  unsigned short* msout = (unsigned short*)(ws + 56164352);         // 22282240 B

  prep_kernel<<<384, 256, 0, stream>>>(W_val, W_off, W_attn, W_out, wtval, wtoa,
                                       wtout);
  gemm_kernel<0><<<dim3(680, 4), 256, 0, stream>>>(
      value, nullptr, wtval, b_val, nullptr, nullptr, vbf, nullptr);
  gemm_kernel<1><<<dim3(680, 6), 256, 0, stream>>>(
      query, nullptr, wtoa, b_off, b_attn, nullptr, offattn, nullptr);
  sampler_kernel<<<5440, 256, 0, stream>>>(vbf, offattn, refpts, msout);
  gemm_kernel<2><<<dim3(680, 4), 256, 0, stream>>>(
      nullptr, msout, wtout, b_out, nullptr, query, nullptr, out);
}